// Round 3
// baseline (187.623 us; speedup 1.0000x reference)
//
#include <hip/hip_runtime.h>
#include <stdint.h>

// 3x3 conv s1 p1, NCHW fp32, 64->128ch, 16x112x112 -> barrier-free implicit GEMM.
// prep: x -> zero-padded NHWC bf16 xt[n][114][114][64]; w -> Wt[tap][oc][ic] bf16.
// conv: block = 128oc x 2 output rows (224 px). 4-row x 114-col halo (58KB) DMA'd to
//       LDS once (global_load_lds w=16, XOR-swizzled chunks), ONE barrier, then
//       9 taps x 56 MFMA/wave with A-frags loaded global->VGPR (L2-hot, vmcnt-pipelined).

#define HW      112
#define PIX     12544
#define ICN     64
#define OCN     128
#define PADW    114
#define PADPIX  12996          // 114*114
#define NIMG    16

#define XT_BYTES  (NIMG * PADPIX * ICN * 2)   // 26,615,808
#define WT_OFF    XT_BYTES                    // + 147,456 weight bytes
#define XPB       204                         // ceil(12996/64) pixel-blocks per image
#define XBLK      (NIMG * XPB)                // 3264
#define WBLK      72
#define CONV_BLK  (NIMG * 56)                 // 896

typedef __attribute__((ext_vector_type(8))) __bf16 bf16x8;
typedef __attribute__((ext_vector_type(4))) float  f32x4;

__device__ __forceinline__ uint32_t rne_lo(float f) {
    uint32_t u = __builtin_bit_cast(uint32_t, f);
    return (u + 0x7fffu + ((u >> 16) & 1u)) >> 16;
}
__device__ __forceinline__ uint32_t pk2(float a, float b) {
    uint32_t ub = __builtin_bit_cast(uint32_t, b);
    ub = (ub + 0x7fffu + ((ub >> 16) & 1u)) & 0xffff0000u;
    return rne_lo(a) | ub;
}
__device__ __forceinline__ void load_lds16(const void* g, void* l) {
    __builtin_amdgcn_global_load_lds(
        (const __attribute__((address_space(1))) uint32_t*)g,
        (__attribute__((address_space(3))) uint32_t*)l, 16, 0, 0);
}

// ---------------- prep ----------------
__global__ void __launch_bounds__(256)
prep(const float* __restrict__ x, const float* __restrict__ w, uint8_t* __restrict__ ws) {
    const int b = blockIdx.x;
    const int t = threadIdx.x;

    if (b < XBLK) {
        const int n  = b / XPB;
        const int pp = (b - n * XPB) * 64 + (t >> 2);   // padded pixel
        const int q  = t & 3;                           // 16-ic quarter
        if (pp >= PADPIX) return;
        char* dst = (char*)ws + ((size_t)(n * PADPIX + pp)) * 128 + q * 32;
        const int hp = pp / PADW;
        const int wp = pp - hp * PADW;
        if (hp >= 1 && hp <= HW && wp >= 1 && wp <= HW) {
            const int p = (hp - 1) * HW + (wp - 1);
            const float* src = x + ((size_t)n * ICN + q * 16) * PIX + p;
            float v[16];
#pragma unroll
            for (int i = 0; i < 16; ++i) v[i] = src[(size_t)i * PIX];
            *(uint4*)dst        = make_uint4(pk2(v[0], v[1]),   pk2(v[2], v[3]),
                                             pk2(v[4], v[5]),   pk2(v[6], v[7]));
            *(uint4*)(dst + 16) = make_uint4(pk2(v[8], v[9]),   pk2(v[10], v[11]),
                                             pk2(v[12], v[13]), pk2(v[14], v[15]));
        } else {
            *(uint4*)dst        = make_uint4(0, 0, 0, 0);
            *(uint4*)(dst + 16) = make_uint4(0, 0, 0, 0);
        }
    } else {
        uint16_t* wt = (uint16_t*)(ws + WT_OFF);
        const int wb = b - XBLK;
#pragma unroll
        for (int k = 0; k < 4; ++k) {
            int wi = wb * 1024 + k * 256 + t;           // [0, 73728)
            int r  = wi >> 13;
            int oc = (wi >> 6) & 127;
            int ic = wi & 63;
            wt[wi] = (uint16_t)rne_lo(w[oc * 576 + ic * 9 + r]);
        }
    }
}

// ---------------- conv ----------------
__global__ void __launch_bounds__(256, 2)
conv_mfma(const uint8_t* __restrict__ ws, const float* __restrict__ bias,
          float* __restrict__ out) {
    __shared__ uint8_t Xs[4 * PADW * 128];   // 58,368 B halo: [hl 0..3][w' 0..113][64ic]

    const char* xt = (const char*)ws;
    const char* wt = (const char*)(ws + WT_OFF);

    const int t = threadIdx.x;
    const int b = blockIdx.x;
    const int n  = b / 56;
    const int tr = b - n * 56;
    const int h0 = tr * 2;                    // output rows h0, h0+1

    const int lane = t & 63;
    const int wave = t >> 6;
    const int lr = lane & 15;
    const int lq = lane >> 4;
    const int oc_base = (wave & 1) * 64;
    const int pxb = wave >> 1;                // 0/1 -> output row h0+pxb

    // ---- halo DMA: 4*114 pixel-rows x 8 chunks = 3648 16B chunks, contiguous region.
    // LDS linear; global side fetches chunk (cpos ^ (row&7)) so readers un-swizzle.
    {
        const char* hbase = xt + ((size_t)(n * PADPIX + h0 * PADW)) * 128;
#pragma unroll
        for (int i = 0; i < 14; ++i) {
            const int idx = i * 256 + t;
            const int r = idx >> 3, c = idx & 7;
            load_lds16(hbase + r * 128 + ((c ^ (r & 7)) * 16),
                       (char*)Xs + (i * 256 + wave * 64) * 16);
        }
        if (wave == 0) {                       // tail: 3584..3647, full wave 0
            const int idx = 14 * 256 + t;
            const int r = idx >> 3, c = idx & 7;
            load_lds16(hbase + r * 128 + ((c ^ (r & 7)) * 16),
                       (char*)Xs + (14 * 256) * 16);
        }
    }
    __syncthreads();   // compiler drains vmcnt before barrier; only barrier in kernel

    f32x4 acc[4][7];
    {
        f32x4 z = {0.f, 0.f, 0.f, 0.f};
#pragma unroll
        for (int i = 0; i < 4; ++i)
#pragma unroll
            for (int j = 0; j < 7; ++j) acc[i][j] = z;
    }

    // per-lane weight base: A[m=lr -> oc][k chunk = kh*4+lq]
    const char* abase = wt + (oc_base + lr) * 128 + lq * 16;

#pragma unroll
    for (int tap = 0; tap < 9; ++tap) {
        const int dy = tap / 3 - 1;
        const int dx = tap - (tap / 3) * 3 - 1;
        // B pixel-row in halo: hl = pxb+dy+1 ; w' = ni*16 + lr + dx + 1
        const int rb = (pxb + dy + 1) * PADW + dx + 1 + lr;
        const int s0 = ((lq)     ^ (rb & 7)) * 16;      // rb&7 invariant in ni (16%8==0)
        const int s1 = ((lq + 4) ^ (rb & 7)) * 16;
        const char* bbase = (const char*)Xs + rb * 128;

        bf16x8 a[8];
#pragma unroll
        for (int mi = 0; mi < 4; ++mi) {
            a[mi * 2]     = *(const bf16x8*)(abase + tap * 16384 + mi * 2048);
            a[mi * 2 + 1] = *(const bf16x8*)(abase + tap * 16384 + mi * 2048 + 64);
        }
#pragma unroll
        for (int ni = 0; ni < 7; ++ni) {
            bf16x8 b0 = *(const bf16x8*)(bbase + ni * 2048 + s0);
            bf16x8 b1 = *(const bf16x8*)(bbase + ni * 2048 + s1);
#pragma unroll
            for (int mi = 0; mi < 4; ++mi) {
                acc[mi][ni] = __builtin_amdgcn_mfma_f32_16x16x32_bf16(
                    a[mi * 2],     b0, acc[mi][ni], 0, 0, 0);
                acc[mi][ni] = __builtin_amdgcn_mfma_f32_16x16x32_bf16(
                    a[mi * 2 + 1], b1, acc[mi][ni], 0, 0, 0);
            }
        }
    }

    // ---- epilogue: D col = lr -> pixel (ow = ni*16+lr), row = lq*4+rg -> oc
    const int oh = h0 + pxb;
#pragma unroll
    for (int mi = 0; mi < 4; ++mi) {
#pragma unroll
        for (int rg = 0; rg < 4; ++rg) {
            const int oc = oc_base + mi * 16 + lq * 4 + rg;
            const float bb = bias[oc];
            float* orow = out + ((size_t)(n * OCN + oc)) * PIX + oh * HW + lr;
#pragma unroll
            for (int ni = 0; ni < 7; ++ni)
                orow[ni * 16] = acc[mi][ni][rg] + bb;
        }
    }
}

extern "C" void kernel_launch(void* const* d_in, const int* in_sizes, int n_in,
                              void* d_out, int out_size, void* d_ws, size_t ws_size,
                              hipStream_t stream) {
    const float* x    = (const float*)d_in[0];
    const float* w    = (const float*)d_in[1];
    const float* bias = (const float*)d_in[2];
    float* out = (float*)d_out;
    uint8_t* ws = (uint8_t*)d_ws;   // needs 26,763,264 bytes

    prep<<<XBLK + WBLK, 256, 0, stream>>>(x, w, ws);
    conv_mfma<<<CONV_BLK, 256, 0, stream>>>(ws, bias, out);
}